// Round 6
// baseline (135.989 us; speedup 1.0000x reference)
//
#include <hip/hip_runtime.h>

#define HH 224
#define WW 224
#define PSD 112
#define NP 12544      // 112*112 patches per plane
#define NBG 1024      // B*G
#define NCH 28        // 4-patch chunks per patch row
#define NTASK (112 * NCH)   // 3136 tasks per plane (= 49 * 64 exactly)

// upper-triangle pair enumeration, row-major: k -> (PI[k], PJ[k]), i<=j
constexpr int PI[45] = {0,0,0,0,0,0,0,0,0, 1,1,1,1,1,1,1,1, 2,2,2,2,2,2,2,
                        3,3,3,3,3,3, 4,4,4,4,4, 5,5,5,5, 6,6,6, 7,7, 8};
constexpr int PJ[45] = {0,1,2,3,4,5,6,7,8, 1,2,3,4,5,6,7,8, 2,3,4,5,6,7,8,
                        3,4,5,6,7,8, 4,5,6,7,8, 5,6,7,8, 6,7,8, 7,8, 8};

// Load L[0..8] = x[r][8t-1 .. 8t+7] (r assumed >= 0)
__device__ __forceinline__ void load_row9(const float* __restrict__ row,
                                          int t, float* L) {
    const int cb = 8 * t;
    L[0] = (t == 0) ? 0.f : row[cb - 1];
    float4 a = *reinterpret_cast<const float4*>(row + cb);
    float4 b = *reinterpret_cast<const float4*>(row + cb + 4);
    L[1] = a.x; L[2] = a.y; L[3] = a.z; L[4] = a.w;
    L[5] = b.x; L[6] = b.y; L[7] = b.z; L[8] = b.w;
}

// One wave accumulates products k in [K0,K1) and sums i in [S0,S1) over ALL
// tasks of the plane, then shuffle-reduces and writes its slice of sh[54].
// Persistent regs: (K1-K0)+(S1-S0) <= 15  ->  fits the 64-VGPR allocation
// the compiler insists on, with zero scratch spill.
template <int K0, int K1, int S0, int S1>
__device__ __forceinline__ void gram_wave(const float* __restrict__ xp,
                                          int lane, float* __restrict__ sh) {
    constexpr int NK = K1 - K0;
    constexpr int NS = S1 - S0;
    float acc[NK];
    float sm[NS];
#pragma unroll
    for (int m = 0; m < NK; ++m) acc[m] = 0.f;
#pragma unroll
    for (int m = 0; m < NS; ++m) sm[m] = 0.f;

    for (int q = 0; q < NTASK / 64; ++q) {
        const int task = q * 64 + lane;
        const int ph = task / NCH;
        const int t = task - ph * NCH;
        const int r0 = 2 * ph - 1;
        float L[3][9];
#pragma unroll
        for (int kr = 0; kr < 3; ++kr) {
            const int r = r0 + kr;
            if (r < 0) {
#pragma unroll
                for (int j = 0; j < 9; ++j) L[kr][j] = 0.f;
            } else {
                load_row9(xp + r * WW, t, L[kr]);
            }
        }
#pragma unroll
        for (int u = 0; u < 4; ++u) {
#pragma unroll
            for (int k = K0; k < K1; ++k) {
                constexpr int z = 0;  // keep k usable in constexpr context below
                (void)z;
                const int i = PI[k], j = PJ[k];
                acc[k - K0] += L[i / 3][2 * u + i % 3] * L[j / 3][2 * u + j % 3];
            }
#pragma unroll
            for (int i2 = S0; i2 < S1; ++i2)
                sm[i2 - S0] += L[i2 / 3][2 * u + i2 % 3];
        }
    }

#pragma unroll
    for (int m = 0; m < NK; ++m) {
        float v = acc[m];
#pragma unroll
        for (int off = 32; off; off >>= 1) v += __shfl_down(v, off, 64);
        if (lane == 0) sh[K0 + m] = v;
    }
#pragma unroll
    for (int m = 0; m < NS; ++m) {
        float v = sm[m];
#pragma unroll
        for (int off = 32; off; off >>= 1) v += __shfl_down(v, off, 64);
        if (lane == 0) sh[45 + S0 + m] = v;
    }
}

__global__ __launch_bounds__(256, 4) void scann_k(
    const float* __restrict__ x,
    const float* __restrict__ Wq, const float* __restrict__ bq,
    const float* __restrict__ Wk, const float* __restrict__ bk,
    const float* __restrict__ Wv, const float* __restrict__ bv,
    const float* __restrict__ Wo, const float* __restrict__ bo,
    float* __restrict__ out) {
    const int bg = blockIdx.x;
    const int g = bg & 63;
    const float* __restrict__ xp = x + (size_t)bg * (HH * WW);
    const int tid = threadIdx.x;
    const int wv = tid >> 6;
    const int lane = tid & 63;

    __shared__ float sh[54];     // gram: 45 upper-tri products + 9 sums
    __shared__ float TT[81];
    __shared__ float Qm_s[9];
    __shared__ float wsh[81];
    __shared__ float cf[10];

    // ------------- Phase 1+2: gram, product-split across waves -------------
    if (wv == 0)      gram_wave<0, 11, 0, 2>(xp, lane, sh);
    else if (wv == 1) gram_wave<11, 22, 2, 4>(xp, lane, sh);
    else if (wv == 2) gram_wave<22, 33, 4, 6>(xp, lane, sh);
    else              gram_wave<33, 45, 6, 9>(xp, lane, sh);
    __syncthreads();

    // ------------- Phase 3: attention-weight solve (9 threads) -------------
#define MIDX(i, j) (9 * (i) - (i) * ((i)-1) / 2 + ((j) - (i)))
#define MAT(i, j) ((i) <= (j) ? sh[MIDX(i, j)] : sh[MIDX(j, i)])
    if (tid < 9) {
        const int t = tid;
        const float* wqt = Wq + g * 81 + t * 9;
        float w[9];
#pragma unroll
        for (int j = 0; j < 9; ++j) w[j] = wqt[j];
        float q = 0.f;
#pragma unroll
        for (int j = 0; j < 9; ++j) q += w[j] * sh[45 + j];
        Qm_s[t] = q;
#pragma unroll
        for (int i = 0; i < 9; ++i) {
            float s = 0.f;
#pragma unroll
            for (int j = 0; j < 9; ++j) s += MAT(i, j) * w[j];
            TT[i * 9 + t] = s;
        }
    }
    __syncthreads();
    if (tid < 9) {
        const int s = tid;
        const float* wks = Wk + g * 81 + s * 9;
        float w[9];
#pragma unroll
        for (int i = 0; i < 9; ++i) w[i] = wks[i];
        float Km = 0.f;
#pragma unroll
        for (int i = 0; i < 9; ++i) Km += w[i] * sh[45 + i];
        const float bks = bk[g * 9 + s];
        float e[9];
#pragma unroll
        for (int t = 0; t < 9; ++t) {
            const float bqt = bq[g * 9 + t];
            float sum = bks * Qm_s[t] + bqt * Km + 12544.f * bks * bqt;
#pragma unroll
            for (int i = 0; i < 9; ++i) sum += w[i] * TT[i * 9 + t];
            e[t] = sum;
        }
        float mx = e[0];
#pragma unroll
        for (int t = 1; t < 9; ++t) mx = fmaxf(mx, e[t]);
        float ex[9], se = 0.f;
#pragma unroll
        for (int t = 0; t < 9; ++t) {
            ex[t] = expf(e[t] - mx);
            se += ex[t];
        }
        const float wos = Wo[g * 9 + s] / se;
#pragma unroll
        for (int t = 0; t < 9; ++t) wsh[s * 9 + t] = wos * ex[t];
    }
    __syncthreads();
    if (tid < 9) {
        const int j = tid;
        float weff[9];
#pragma unroll
        for (int t = 0; t < 9; ++t) {
            float s = 0.f;
#pragma unroll
            for (int s2 = 0; s2 < 9; ++s2) s += wsh[s2 * 9 + t];
            weff[t] = s;
        }
        float cj = 0.f;
#pragma unroll
        for (int t = 0; t < 9; ++t) cj += weff[t] * Wv[g * 81 + t * 9 + j];
        cf[j] = cj;
        if (j == 0) {
            float d = bo[g];
#pragma unroll
            for (int t = 0; t < 9; ++t) d += weff[t] * bv[g * 9 + t];
            cf[9] = d;
        }
    }
    __syncthreads();

    // ------------- Phase 4: 3x3 stride-2 conv (tasks split by thread) ------
    float cc[9];
#pragma unroll
    for (int j = 0; j < 9; ++j) cc[j] = cf[j];
    const float dd = cf[9];
    float* __restrict__ op = out + (size_t)bg * NP;

    for (int task = tid; task < NTASK; task += 256) {
        const int ph = task / NCH;
        const int t = task - ph * NCH;
        const int r0 = 2 * ph - 1;
        float L[3][9];
#pragma unroll
        for (int kr = 0; kr < 3; ++kr) {
            const int r = r0 + kr;
            if (r < 0) {
#pragma unroll
                for (int j = 0; j < 9; ++j) L[kr][j] = 0.f;
            } else {
                load_row9(xp + r * WW, t, L[kr]);
            }
        }
        float o[4];
#pragma unroll
        for (int u = 0; u < 4; ++u) {
            float s = dd;
#pragma unroll
            for (int kh = 0; kh < 3; ++kh)
#pragma unroll
                for (int kw = 0; kw < 3; ++kw)
                    s += cc[3 * kh + kw] * L[kh][2 * u + kw];
            o[u] = s;
        }
        *reinterpret_cast<float4*>(op + ph * PSD + 4 * t) =
            make_float4(o[0], o[1], o[2], o[3]);
    }
}

extern "C" void kernel_launch(void* const* d_in, const int* in_sizes, int n_in,
                              void* d_out, int out_size, void* d_ws, size_t ws_size,
                              hipStream_t stream) {
    const float* x = (const float*)d_in[0];
    const float* Wq = (const float*)d_in[1];
    const float* bq = (const float*)d_in[2];
    const float* Wk = (const float*)d_in[3];
    const float* bk = (const float*)d_in[4];
    const float* Wv = (const float*)d_in[5];
    const float* bv = (const float*)d_in[6];
    const float* Wo = (const float*)d_in[7];
    const float* bo = (const float*)d_in[8];
    float* out = (float*)d_out;

    scann_k<<<NBG, 256, 0, stream>>>(x, Wq, bq, Wk, bk, Wv, bv, Wo, bo, out);
}